// Round 8
// baseline (128.944 us; speedup 1.0000x reference)
//
#include <hip/hip_runtime.h>

#define NPTS 16384
#define NB   8
#define NM   2048
#define NC   128
#define EPSF 1e-8f

#define TQ   32                     // threads per query group
#define QPT  2                      // queries per group (each thread: 2 indep chains)
#define QPB  16                     // queries per 256-thread block (8 groups x 2)
#define GX   160                    // blocks per batch: 2560 slots >> segN(~2100) -> no tail

// u64 key = (float_bits(d) << 32) | j : for d >= 0, u64 '<' == lexicographic (d, idx) '<'.
// Branchless (R5 lesson: guard is ~always wave-taken, only adds exec churn).
#define MERGE_KEY(K0, K1, K2, e) do {                   \
    const bool _b2 = (e) < K2;                          \
    const bool _b1 = (e) < K1;                          \
    const bool _b0 = (e) < K0;                          \
    K2 = _b1 ? K1 : (_b2 ? (e) : K2);                   \
    K1 = _b0 ? K0 : (_b1 ? (e) : K1);                   \
    K0 = _b0 ? (e) : K0;                                \
} while (0)

// ONE dispatch, no workspace.
// Block (batch b, window x): scan binds -> ranks; early-exit empty; stage batch b's
// points in LDS (SoA float2 + float, ~24.7 KB -> 6 blocks/CU); 3-NN with TQ=32 threads
// per 2 queries (1 LDS point read feeds 2 key-chains); gather from raw (B,C,m) feats.
__global__ __launch_bounds__(256, 4) void fused(const float* __restrict__ unknown,
                                                const float* __restrict__ known,
                                                const int*   __restrict__ binds,
                                                const float* __restrict__ feats,
                                                float* __restrict__ out) {
    __shared__ float2 kxy[NM];      // 16 KB
    __shared__ float  kz[NM];       // 8 KB
    __shared__ int qlist[QPB];
    __shared__ int wsum[4];

    const int tid  = threadIdx.x;
    const int b    = blockIdx.y;
    const int x    = blockIdx.x;
    const int lane = tid & 63;
    const int wave = tid >> 6;

    // ---- scan binds: per-thread count of batch-b points, 256-thread exclusive prefix ----
    const int4* b4 = (const int4*)binds;   // thread t owns binds[t*64 .. t*64+63]
    int myCnt = 0;
#pragma unroll
    for (int r = 0; r < 16; ++r) {
        const int4 v = b4[tid * 16 + r];
        myCnt += (v.x == b) + (v.y == b) + (v.z == b) + (v.w == b);
    }
    int inc = myCnt;
#pragma unroll
    for (int off = 1; off <= 32; off <<= 1) {
        const int n = __shfl_up(inc, off);
        if (lane >= off) inc += n;
    }
    if (lane == 63) wsum[wave] = inc;
    __syncthreads();
    int wbase = 0;
    for (int w = 0; w < wave; ++w) wbase += wsum[w];
    const int exPre = wbase + inc - myCnt;
    const int segN  = wsum[0] + wsum[1] + wsum[2] + wsum[3];

    if (x * QPB >= segN) return;           // block-uniform early exit

    // ---- stage known points of batch b into LDS (SoA) ----
    {
        const float* kb = known + (size_t)b * NM * 3;
        for (int j = tid; j < NM; j += 256) {
            float2 xy; xy.x = kb[j * 3 + 0]; xy.y = kb[j * 3 + 1];
            kxy[j] = xy;
            kz[j]  = kb[j * 3 + 2];
        }
    }

    const int g = tid >> 5;    // group 0..7 (serves queries 2g, 2g+1)
    const int t = tid & 31;    // thread within group

    // ---- window loop (executes once since GX*QPB >= segN; mop-up kept as safety net) ----
    for (int w0 = x * QPB; w0 < segN; w0 += GX * QPB) {
        __syncthreads();       // staging complete / previous window's qlist reads done
        if (exPre < w0 + QPB && exPre + myCnt > w0) {
            int rank = exPre;
#pragma unroll
            for (int r = 0; r < 16; ++r) {
                const int4 v = b4[tid * 16 + r];
                const int base = tid * 64 + r * 4;
                if (v.x == b) { if (rank >= w0 && rank < w0 + QPB) qlist[rank - w0] = base + 0; ++rank; }
                if (v.y == b) { if (rank >= w0 && rank < w0 + QPB) qlist[rank - w0] = base + 1; ++rank; }
                if (v.z == b) { if (rank >= w0 && rank < w0 + QPB) qlist[rank - w0] = base + 2; ++rank; }
                if (v.w == b) { if (rank >= w0 && rank < w0 + QPB) qlist[rank - w0] = base + 3; ++rank; }
            }
        }
        __syncthreads();

        const int valid = (segN - w0 < QPB) ? (segN - w0) : QPB;
        const int q0i   = (2 * g + 0 < valid) ? (2 * g + 0) : 0;
        const int q1i   = (2 * g + 1 < valid) ? (2 * g + 1) : 0;
        const int pA    = qlist[q0i];      // duplicate query -> identical bytes, benign
        const int pB    = qlist[q1i];
        const float uxA = unknown[pA * 3 + 0], uyA = unknown[pA * 3 + 1], uzA = unknown[pA * 3 + 2];
        const float uxB = unknown[pB * 3 + 0], uyB = unknown[pB * 3 + 1], uzB = unknown[pB * 3 + 2];

        unsigned long long A0 = ~0ull, A1 = ~0ull, A2 = ~0ull;
        unsigned long long B0 = ~0ull, B1 = ~0ull, B2 = ~0ull;

        // explicit prefetch: load iter i+1's point before merging iter i
        float2 xy = kxy[t];
        float  zz = kz[t];
#pragma unroll 4
        for (int i = 0; i < NM / TQ; ++i) {
            const int j = (i << 5) | t;
            const float2 cxy = xy;
            const float  cz  = zz;
            if (i + 1 < NM / TQ) {
                xy = kxy[j + TQ];
                zz = kz[j + TQ];
            }
            // strict rn, numpy association ((dx2+dy2)+dz2): selection bit-identical to ref
            const float dxA = __fsub_rn(uxA, cxy.x);
            const float dyA = __fsub_rn(uyA, cxy.y);
            const float dzA = __fsub_rn(uzA, cz);
            const float dA  = __fadd_rn(__fadd_rn(__fmul_rn(dxA, dxA), __fmul_rn(dyA, dyA)),
                                        __fmul_rn(dzA, dzA));
            const float dxB = __fsub_rn(uxB, cxy.x);
            const float dyB = __fsub_rn(uyB, cxy.y);
            const float dzB = __fsub_rn(uzB, cz);
            const float dB  = __fadd_rn(__fadd_rn(__fmul_rn(dxB, dxB), __fmul_rn(dyB, dyB)),
                                        __fmul_rn(dzB, dzB));
            const unsigned long long keyA =
                ((unsigned long long)__float_as_uint(dA) << 32) | (unsigned)j;
            const unsigned long long keyB =
                ((unsigned long long)__float_as_uint(dB) << 32) | (unsigned)j;
            MERGE_KEY(A0, A1, A2, keyA);
            MERGE_KEY(B0, B1, B2, keyB);
        }

        // merge 32 partial top-3 lists per chain (shfl_down tree within 32-lane halves;
        // lane 0 of each half accumulates only same-group partials), broadcast
#pragma unroll
        for (int off = 16; off >= 1; off >>= 1) {
            const unsigned long long a0 = __shfl_down(A0, off);
            const unsigned long long a1 = __shfl_down(A1, off);
            const unsigned long long a2 = __shfl_down(A2, off);
            MERGE_KEY(A0, A1, A2, a0);
            MERGE_KEY(A0, A1, A2, a1);
            MERGE_KEY(A0, A1, A2, a2);
            const unsigned long long c0 = __shfl_down(B0, off);
            const unsigned long long c1 = __shfl_down(B1, off);
            const unsigned long long c2 = __shfl_down(B2, off);
            MERGE_KEY(B0, B1, B2, c0);
            MERGE_KEY(B0, B1, B2, c1);
            MERGE_KEY(B0, B1, B2, c2);
        }
        const int src = lane & ~31;
        A0 = __shfl(A0, src); A1 = __shfl(A1, src); A2 = __shfl(A2, src);
        B0 = __shfl(B0, src); B1 = __shfl(B1, src); B2 = __shfl(B2, src);

        const float* fb = feats + (size_t)b * NC * NM;
#pragma unroll
        for (int q = 0; q < QPT; ++q) {
            const unsigned long long K0 = q ? B0 : A0;
            const unsigned long long K1 = q ? B1 : A1;
            const unsigned long long K2 = q ? B2 : A2;
            const int p = q ? pB : pA;

            const float d0 = __uint_as_float((unsigned)(K0 >> 32));
            const float d1 = __uint_as_float((unsigned)(K1 >> 32));
            const float d2 = __uint_as_float((unsigned)(K2 >> 32));
            const int   i0 = (int)(unsigned)K0;
            const int   i1 = (int)(unsigned)K1;
            const int   i2 = (int)(unsigned)K2;

            const float t0 = 1.0f / (sqrtf(d0) + EPSF);
            const float t1 = 1.0f / (sqrtf(d1) + EPSF);
            const float t2 = 1.0f / (sqrtf(d2) + EPSF);
            const float s  = t0 + t1 + t2;
            const float w0w = t0 / s, w1w = t1 / s, w2w = t2 / s;

            // gather from raw (B,C,m): column reads, L2/L3-resident (feats = 8 MB)
#pragma unroll
            for (int k = 0; k < 4; ++k) {
                const int c = t + (k << 5);        // 32 lanes -> 128B-coalesced out rows
                const float* fc = fb + (size_t)c * NM;
                const float f0 = fc[i0];
                const float f1 = fc[i1];
                const float f2 = fc[i2];
                out[(size_t)p * NC + c] = w0w * f0 + w1w * f1 + w2w * f2;
            }
        }
    }
}

extern "C" void kernel_launch(void* const* d_in, const int* in_sizes, int n_in,
                              void* d_out, int out_size, void* d_ws, size_t ws_size,
                              hipStream_t stream) {
    const float* unknown = (const float*)d_in[0];   // (n, 3)
    const float* known   = (const float*)d_in[1];   // (B, m, 3)
    const int*   binds   = (const int*)d_in[2];     // (n,)
    const float* feats   = (const float*)d_in[3];   // (B, C, m)
    float*       out     = (float*)d_out;           // (n, C, 1)

    fused<<<dim3(GX, NB), 256, 0, stream>>>(unknown, known, binds, feats, out);
}

// Round 9
// 120.012 us; speedup vs baseline: 1.0744x; 1.0744x over previous
//
#include <hip/hip_runtime.h>

#define NPTS 16384
#define NB   8
#define NM   2048
#define NC   128
#define EPSF 1e-8f

#define TQ   32                     // threads per query
#define QPB  16                     // queries per 512-thread block (16 groups of 32)
#define GX   132                    // blocks per batch: 2112 slots ~ segN(~2090); window loop covers overflow

// u64 key = (float_bits(d) << 32) | j : for d >= 0, u64 '<' == lexicographic (d, idx) '<'.
// Branchless (R5 lesson).
#define MERGE_KEY(K0, K1, K2, e) do {                   \
    const bool _b2 = (e) < K2;                          \
    const bool _b1 = (e) < K1;                          \
    const bool _b0 = (e) < K0;                          \
    K2 = _b1 ? K1 : (_b2 ? (e) : K2);                   \
    K1 = _b0 ? K0 : (_b1 ? (e) : K1);                   \
    K0 = _b0 ? (e) : K0;                                \
} while (0)

// ONE dispatch. 512-thread blocks (8 waves): TQ=32, 1 query per 32-lane group ->
// 2 queries/wave -> 8192 waves total = 32 waves/CU possible (the R8 lesson: runtime
// ~ work / resident-waves; TQ=16's 4096 waves capped occupancy at 50%).
// LDS: float4 points (32KB) x 4 blocks/CU = 132KB <= 160KB.
__global__ __launch_bounds__(512, 8) void fused(const float* __restrict__ unknown,
                                                const float* __restrict__ known,
                                                const int*   __restrict__ binds,
                                                const float* __restrict__ feats,
                                                float* __restrict__ out) {
    __shared__ float4 kpt[NM];      // 32 KB, w unused
    __shared__ int qlist[QPB];
    __shared__ int wsum[8];

    const int tid  = threadIdx.x;
    const int b    = blockIdx.y;
    const int x    = blockIdx.x;
    const int lane = tid & 63;
    const int wave = tid >> 6;

    // ---- scan binds: per-thread count of batch-b points (32 each), 512-thread prefix ----
    const int4* b4 = (const int4*)binds;   // thread t owns binds[t*32 .. t*32+31]
    int myCnt = 0;
#pragma unroll
    for (int r = 0; r < 8; ++r) {
        const int4 v = b4[tid * 8 + r];
        myCnt += (v.x == b) + (v.y == b) + (v.z == b) + (v.w == b);
    }
    int inc = myCnt;
#pragma unroll
    for (int off = 1; off <= 32; off <<= 1) {
        const int n = __shfl_up(inc, off);
        if (lane >= off) inc += n;
    }
    if (lane == 63) wsum[wave] = inc;
    __syncthreads();
    int wbase = 0;
    for (int w = 0; w < wave; ++w) wbase += wsum[w];
    const int exPre = wbase + inc - myCnt;
    int segN = 0;
#pragma unroll
    for (int w = 0; w < 8; ++w) segN += wsum[w];

    if (x * QPB >= segN) return;           // block-uniform early exit

    // ---- stage known points of batch b into LDS (float4 -> 1 ds_read_b128 in hot loop) ----
    {
        const float* kb = known + (size_t)b * NM * 3;
        for (int j = tid; j < NM; j += 512) {
            float4 kp;
            kp.x = kb[j * 3 + 0];
            kp.y = kb[j * 3 + 1];
            kp.z = kb[j * 3 + 2];
            kp.w = 0.0f;
            kpt[j] = kp;
        }
    }

    const int g = tid >> 5;    // group 0..15 -> query g of the window
    const int t = tid & 31;    // thread within group

    // ---- window loop (once for GX*QPB >= segN; safety net otherwise) ----
    for (int w0 = x * QPB; w0 < segN; w0 += GX * QPB) {
        __syncthreads();       // staging complete / previous window's qlist reads done
        if (exPre < w0 + QPB && exPre + myCnt > w0) {
            int rank = exPre;
#pragma unroll
            for (int r = 0; r < 8; ++r) {
                const int4 v = b4[tid * 8 + r];
                const int base = tid * 32 + r * 4;
                if (v.x == b) { if (rank >= w0 && rank < w0 + QPB) qlist[rank - w0] = base + 0; ++rank; }
                if (v.y == b) { if (rank >= w0 && rank < w0 + QPB) qlist[rank - w0] = base + 1; ++rank; }
                if (v.z == b) { if (rank >= w0 && rank < w0 + QPB) qlist[rank - w0] = base + 2; ++rank; }
                if (v.w == b) { if (rank >= w0 && rank < w0 + QPB) qlist[rank - w0] = base + 3; ++rank; }
            }
        }
        __syncthreads();

        const int valid = (segN - w0 < QPB) ? (segN - w0) : QPB;
        const int kq    = (g < valid) ? g : 0;   // duplicate query -> identical bytes, benign
        const int p     = qlist[kq];
        const float ux = unknown[p * 3 + 0];
        const float uy = unknown[p * 3 + 1];
        const float uz = unknown[p * 3 + 2];

        unsigned long long K0 = ~0ull, K1 = ~0ull, K2 = ~0ull;

        // explicit 1-ahead prefetch
        float4 kp = kpt[t];
#pragma unroll 4
        for (int i = 0; i < NM / TQ; ++i) {
            const int j = (i << 5) | t;
            const float4 c = kp;
            if (i + 1 < NM / TQ) kp = kpt[j + TQ];
            // strict rn, numpy association ((dx2+dy2)+dz2): selection bit-identical to ref
            const float dx = __fsub_rn(ux, c.x);
            const float dy = __fsub_rn(uy, c.y);
            const float dz = __fsub_rn(uz, c.z);
            const float d  = __fadd_rn(__fadd_rn(__fmul_rn(dx, dx), __fmul_rn(dy, dy)),
                                       __fmul_rn(dz, dz));
            const unsigned long long key =
                ((unsigned long long)__float_as_uint(d) << 32) | (unsigned)j;
            MERGE_KEY(K0, K1, K2, key);
        }

        // merge 32 partials within the group (shfl_down: lane g*32's chain pulls only
        // in-group lanes; cross-boundary lanes hold garbage but are never read)
#pragma unroll
        for (int off = 16; off >= 1; off >>= 1) {
            const unsigned long long e0 = __shfl_down(K0, off);
            const unsigned long long e1 = __shfl_down(K1, off);
            const unsigned long long e2 = __shfl_down(K2, off);
            MERGE_KEY(K0, K1, K2, e0);
            MERGE_KEY(K0, K1, K2, e1);
            MERGE_KEY(K0, K1, K2, e2);
        }
        const int src = lane & ~31;
        K0 = __shfl(K0, src); K1 = __shfl(K1, src); K2 = __shfl(K2, src);

        const float d0 = __uint_as_float((unsigned)(K0 >> 32));
        const float d1 = __uint_as_float((unsigned)(K1 >> 32));
        const float d2 = __uint_as_float((unsigned)(K2 >> 32));
        const int   i0 = (int)(unsigned)K0;
        const int   i1 = (int)(unsigned)K1;
        const int   i2 = (int)(unsigned)K2;

        const float t0 = 1.0f / (sqrtf(d0) + EPSF);
        const float t1 = 1.0f / (sqrtf(d1) + EPSF);
        const float t2 = 1.0f / (sqrtf(d2) + EPSF);
        const float s  = t0 + t1 + t2;
        const float w0w = t0 / s, w1w = t1 / s, w2w = t2 / s;

        // gather from raw (B,C,m): column reads, L2/L3-resident (feats = 8 MB)
        const float* fb = feats + (size_t)b * NC * NM;
#pragma unroll
        for (int k = 0; k < 4; ++k) {
            const int c = t + (k << 5);        // 32 lanes -> 128B-coalesced out rows
            const float* fc = fb + (size_t)c * NM;
            const float f0 = fc[i0];
            const float f1 = fc[i1];
            const float f2 = fc[i2];
            out[(size_t)p * NC + c] = w0w * f0 + w1w * f1 + w2w * f2;
        }
    }
}

extern "C" void kernel_launch(void* const* d_in, const int* in_sizes, int n_in,
                              void* d_out, int out_size, void* d_ws, size_t ws_size,
                              hipStream_t stream) {
    const float* unknown = (const float*)d_in[0];   // (n, 3)
    const float* known   = (const float*)d_in[1];   // (B, m, 3)
    const int*   binds   = (const int*)d_in[2];     // (n,)
    const float* feats   = (const float*)d_in[3];   // (B, C, m)
    float*       out     = (float*)d_out;           // (n, C, 1)

    fused<<<dim3(GX, NB), 512, 0, stream>>>(unknown, known, binds, feats, out);
}

// Round 10
// 113.678 us; speedup vs baseline: 1.1343x; 1.0557x over previous
//
#include <hip/hip_runtime.h>

#define NPTS 16384
#define NB   8
#define NM   2048
#define NC   128
#define EPSF 1e-8f

#define TQ   16                     // threads per query
#define QPB  16                     // queries per 256-thread block
#define GX   160                    // blocks per batch: 2560 slots >> segN(~2100) -> no tail

// Hot-loop merge: f32 distances + i32 indices in separate regs (32-bit cndmasks only;
// the u64-key version cost ~2x VALU — R9 lesson). Strict '<' keeps earliest j on ties
// (per-thread j strictly increases -> matches top_k lowest-index tie-break).
#define MERGE_F(d, j) do {                              \
    const bool _b2 = (d) < D2;                          \
    const bool _b1 = (d) < D1;                          \
    const bool _b0 = (d) < D0;                          \
    D2 = _b1 ? D1 : (_b2 ? (d) : D2);                   \
    I2 = _b1 ? I1 : (_b2 ? (j) : I2);                   \
    D1 = _b0 ? D0 : (_b1 ? (d) : D1);                   \
    I1 = _b0 ? I0 : (_b1 ? (j) : I1);                   \
    D0 = _b0 ? (d) : D0;                                \
    I0 = _b0 ? (j) : I0;                                \
} while (0)

// Cross-thread merge element: full lexicographic (d, idx) compare (runs once per query)
#define MERGE_DI(ed, ei) do {                                           \
    const bool _b2 = ((ed) < D2) || (((ed) == D2) && ((ei) < I2));      \
    const bool _b1 = ((ed) < D1) || (((ed) == D1) && ((ei) < I1));      \
    const bool _b0 = ((ed) < D0) || (((ed) == D0) && ((ei) < I0));      \
    D2 = _b1 ? D1 : (_b2 ? (ed) : D2);                                  \
    I2 = _b1 ? I1 : (_b2 ? (ei) : I2);                                  \
    D1 = _b0 ? D0 : (_b1 ? (ed) : D1);                                  \
    I1 = _b0 ? I0 : (_b1 ? (ei) : I1);                                  \
    D0 = _b0 ? (ed) : D0;                                               \
    I0 = _b0 ? (ei) : I0;                                               \
} while (0)

// ONE dispatch, no workspace (R6 structure, f32/i32 merge).
__global__ __launch_bounds__(256, 5) void fused(const float* __restrict__ unknown,
                                                const float* __restrict__ known,
                                                const int*   __restrict__ binds,
                                                const float* __restrict__ feats,
                                                float* __restrict__ out) {
    __shared__ float2 kxy[NM];      // 16 KB
    __shared__ float  kz[NM];       // 8 KB
    __shared__ int qlist[QPB];
    __shared__ int wsum[4];

    const int tid  = threadIdx.x;
    const int b    = blockIdx.y;
    const int x    = blockIdx.x;
    const int lane = tid & 63;
    const int wave = tid >> 6;

    // ---- scan binds: per-thread count of batch-b points, 256-thread exclusive prefix ----
    const int4* b4 = (const int4*)binds;   // thread t owns binds[t*64 .. t*64+63]
    int myCnt = 0;
#pragma unroll
    for (int r = 0; r < 16; ++r) {
        const int4 v = b4[tid * 16 + r];
        myCnt += (v.x == b) + (v.y == b) + (v.z == b) + (v.w == b);
    }
    int inc = myCnt;
#pragma unroll
    for (int off = 1; off <= 32; off <<= 1) {
        const int n = __shfl_up(inc, off);
        if (lane >= off) inc += n;
    }
    if (lane == 63) wsum[wave] = inc;
    __syncthreads();
    int wbase = 0;
    for (int w = 0; w < wave; ++w) wbase += wsum[w];
    const int exPre = wbase + inc - myCnt;
    const int segN  = wsum[0] + wsum[1] + wsum[2] + wsum[3];

    if (x * QPB >= segN) return;           // block-uniform early exit

    // ---- stage known points of batch b into LDS (SoA) ----
    {
        const float* kb = known + (size_t)b * NM * 3;
        for (int j = tid; j < NM; j += 256) {
            float2 xy; xy.x = kb[j * 3 + 0]; xy.y = kb[j * 3 + 1];
            kxy[j] = xy;
            kz[j]  = kb[j * 3 + 2];
        }
    }

    const int qi = tid >> 4;   // query within block, 0..15
    const int t  = tid & 15;   // thread within query group

    // ---- window loop (executes once since GX*QPB >= segN; mop-up kept as safety net) ----
    for (int w0 = x * QPB; w0 < segN; w0 += GX * QPB) {
        __syncthreads();       // staging complete / previous window's qlist reads done
        if (exPre < w0 + QPB && exPre + myCnt > w0) {
            int rank = exPre;
#pragma unroll
            for (int r = 0; r < 16; ++r) {
                const int4 v = b4[tid * 16 + r];
                const int base = tid * 64 + r * 4;
                if (v.x == b) { if (rank >= w0 && rank < w0 + QPB) qlist[rank - w0] = base + 0; ++rank; }
                if (v.y == b) { if (rank >= w0 && rank < w0 + QPB) qlist[rank - w0] = base + 1; ++rank; }
                if (v.z == b) { if (rank >= w0 && rank < w0 + QPB) qlist[rank - w0] = base + 2; ++rank; }
                if (v.w == b) { if (rank >= w0 && rank < w0 + QPB) qlist[rank - w0] = base + 3; ++rank; }
            }
        }
        __syncthreads();

        const int valid = (segN - w0 < QPB) ? (segN - w0) : QPB;
        const int kq    = (qi < valid) ? qi : 0;   // duplicate query -> identical bytes, benign
        const int p     = qlist[kq];
        const float ux = unknown[p * 3 + 0];
        const float uy = unknown[p * 3 + 1];
        const float uz = unknown[p * 3 + 2];

        float D0 = __builtin_inff(), D1 = __builtin_inff(), D2 = __builtin_inff();
        int   I0 = NM, I1 = NM, I2 = NM;

#pragma unroll 8
        for (int i = 0; i < NM / TQ; ++i) {
            const int j = (i << 4) | t;
            const float2 kp = kxy[j];
            const float  kzz = kz[j];
            // strict rn, numpy association ((dx2+dy2)+dz2): selection bit-identical to ref
            const float dx = __fsub_rn(ux, kp.x);
            const float dy = __fsub_rn(uy, kp.y);
            const float dz = __fsub_rn(uz, kzz);
            const float d  = __fadd_rn(__fadd_rn(__fmul_rn(dx, dx), __fmul_rn(dy, dy)),
                                       __fmul_rn(dz, dz));
            MERGE_F(d, j);
        }

        // merge 16 partial top-3 lists (shfl_down tree; valid at group lane 0), broadcast
#pragma unroll
        for (int off = 8; off >= 1; off >>= 1) {
            const float e0d = __shfl_down(D0, off);
            const float e1d = __shfl_down(D1, off);
            const float e2d = __shfl_down(D2, off);
            const int   e0i = __shfl_down(I0, off);
            const int   e1i = __shfl_down(I1, off);
            const int   e2i = __shfl_down(I2, off);
            MERGE_DI(e0d, e0i);
            MERGE_DI(e1d, e1i);
            MERGE_DI(e2d, e2i);
        }
        const int src = lane & ~15;
        D0 = __shfl(D0, src); D1 = __shfl(D1, src); D2 = __shfl(D2, src);
        I0 = __shfl(I0, src); I1 = __shfl(I1, src); I2 = __shfl(I2, src);

        const float t0 = 1.0f / (sqrtf(D0) + EPSF);
        const float t1 = 1.0f / (sqrtf(D1) + EPSF);
        const float t2 = 1.0f / (sqrtf(D2) + EPSF);
        const float s  = t0 + t1 + t2;
        const float w0w = t0 / s, w1w = t1 / s, w2w = t2 / s;

        // gather from raw (B,C,m): column reads, L2/L3-resident (feats = 8 MB)
        const float* fb = feats + (size_t)b * NC * NM;
#pragma unroll
        for (int k = 0; k < 8; ++k) {
            const int c = t + (k << 4);            // 16 lanes -> 64B-coalesced out rows
            const float* fc = fb + (size_t)c * NM;
            const float f0 = fc[I0];
            const float f1 = fc[I1];
            const float f2 = fc[I2];
            out[(size_t)p * NC + c] = w0w * f0 + w1w * f1 + w2w * f2;
        }
    }
}

extern "C" void kernel_launch(void* const* d_in, const int* in_sizes, int n_in,
                              void* d_out, int out_size, void* d_ws, size_t ws_size,
                              hipStream_t stream) {
    const float* unknown = (const float*)d_in[0];   // (n, 3)
    const float* known   = (const float*)d_in[1];   // (B, m, 3)
    const int*   binds   = (const int*)d_in[2];     // (n,)
    const float* feats   = (const float*)d_in[3];   // (B, C, m)
    float*       out     = (float*)d_out;           // (n, C, 1)

    fused<<<dim3(GX, NB), 256, 0, stream>>>(unknown, known, binds, feats, out);
}

// Round 11
// 110.617 us; speedup vs baseline: 1.1657x; 1.0277x over previous
//
#include <hip/hip_runtime.h>

#define NPTS 16384
#define NB   8
#define NM   2048
#define NC   128
#define EPSF 1e-8f

#define TQ   16                     // threads per query
#define QPB  16                     // queries per 256-thread block
#define GX   160                    // blocks per batch: 2560 slots >> segN(~2100) -> no tail

// Sorted top-3 insert via min/med3 (3 VALU for the distance regs) + 5 cndmask for
// indices (strict '<' -> earliest j kept on ties; per-thread j strictly increases).
// Equivalence verified by cases: d<D0 / D0<=d<D1 / d==D1 / D1<=d<D2 / d>=D2.
#define MERGE3(d, j) do {                                       \
    const bool _b0 = (d) < D0;                                  \
    const bool _b1 = (d) < D1;                                  \
    const bool _b2 = (d) < D2;                                  \
    const float _n0 = fminf((d), D0);                           \
    const float _n1 = __builtin_amdgcn_fmed3f(D0, D1, (d));     \
    const float _n2 = __builtin_amdgcn_fmed3f(D1, D2, (d));     \
    I2 = _b1 ? I1 : (_b2 ? (j) : I2);                           \
    I1 = _b0 ? I0 : (_b1 ? (j) : I1);                           \
    I0 = _b0 ? (j) : I0;                                        \
    D0 = _n0; D1 = _n1; D2 = _n2;                               \
} while (0)

// Cross-thread merge element: full lexicographic (d, idx) compare (once per query)
#define MERGE_DI(ed, ei) do {                                           \
    const bool _b2 = ((ed) < D2) || (((ed) == D2) && ((ei) < I2));      \
    const bool _b1 = ((ed) < D1) || (((ed) == D1) && ((ei) < I1));      \
    const bool _b0 = ((ed) < D0) || (((ed) == D0) && ((ei) < I0));      \
    D2 = _b1 ? D1 : (_b2 ? (ed) : D2);                                  \
    I2 = _b1 ? I1 : (_b2 ? (ei) : I2);                                  \
    D1 = _b0 ? D0 : (_b1 ? (ed) : D1);                                  \
    I1 = _b0 ? I0 : (_b1 ? (ei) : I1);                                  \
    D0 = _b0 ? (ed) : D0;                                               \
    I0 = _b0 ? (ei) : I0;                                               \
} while (0)

// ONE dispatch, no workspace (R6/R10 structure; hot loop: 2 points/iter, float2 SoA LDS,
// min/med3 merge).
__global__ __launch_bounds__(256, 4) void fused(const float* __restrict__ unknown,
                                                const float* __restrict__ known,
                                                const int*   __restrict__ binds,
                                                const float* __restrict__ feats,
                                                float* __restrict__ out) {
    __shared__ float2 kx2[NM / 2];  // 8 KB: {x[2p], x[2p+1]}
    __shared__ float2 ky2[NM / 2];  // 8 KB
    __shared__ float2 kz2[NM / 2];  // 8 KB
    __shared__ int qlist[QPB];
    __shared__ int wsum[4];

    const int tid  = threadIdx.x;
    const int b    = blockIdx.y;
    const int x    = blockIdx.x;
    const int lane = tid & 63;
    const int wave = tid >> 6;

    // ---- scan binds: per-thread count of batch-b points, 256-thread exclusive prefix ----
    const int4* b4 = (const int4*)binds;   // thread t owns binds[t*64 .. t*64+63]
    int myCnt = 0;
#pragma unroll
    for (int r = 0; r < 16; ++r) {
        const int4 v = b4[tid * 16 + r];
        myCnt += (v.x == b) + (v.y == b) + (v.z == b) + (v.w == b);
    }
    int inc = myCnt;
#pragma unroll
    for (int off = 1; off <= 32; off <<= 1) {
        const int n = __shfl_up(inc, off);
        if (lane >= off) inc += n;
    }
    if (lane == 63) wsum[wave] = inc;
    __syncthreads();
    int wbase = 0;
    for (int w = 0; w < wave; ++w) wbase += wsum[w];
    const int exPre = wbase + inc - myCnt;
    const int segN  = wsum[0] + wsum[1] + wsum[2] + wsum[3];

    if (x * QPB >= segN) return;           // block-uniform early exit

    // ---- stage known points of batch b into pair-SoA LDS ----
    {
        const float* kb = known + (size_t)b * NM * 3;
        for (int p = tid; p < NM / 2; p += 256) {
            const float* s = kb + p * 6;
            float2 vx, vy, vz;
            vx.x = s[0]; vy.x = s[1]; vz.x = s[2];
            vx.y = s[3]; vy.y = s[4]; vz.y = s[5];
            kx2[p] = vx; ky2[p] = vy; kz2[p] = vz;
        }
    }

    const int qi = tid >> 4;   // query within block, 0..15
    const int t  = tid & 15;   // thread within query group

    // ---- window loop (executes once since GX*QPB >= segN; mop-up kept as safety net) ----
    for (int w0 = x * QPB; w0 < segN; w0 += GX * QPB) {
        __syncthreads();       // staging complete / previous window's qlist reads done
        if (exPre < w0 + QPB && exPre + myCnt > w0) {
            int rank = exPre;
#pragma unroll
            for (int r = 0; r < 16; ++r) {
                const int4 v = b4[tid * 16 + r];
                const int base = tid * 64 + r * 4;
                if (v.x == b) { if (rank >= w0 && rank < w0 + QPB) qlist[rank - w0] = base + 0; ++rank; }
                if (v.y == b) { if (rank >= w0 && rank < w0 + QPB) qlist[rank - w0] = base + 1; ++rank; }
                if (v.z == b) { if (rank >= w0 && rank < w0 + QPB) qlist[rank - w0] = base + 2; ++rank; }
                if (v.w == b) { if (rank >= w0 && rank < w0 + QPB) qlist[rank - w0] = base + 3; ++rank; }
            }
        }
        __syncthreads();

        const int valid = (segN - w0 < QPB) ? (segN - w0) : QPB;
        const int kq    = (qi < valid) ? qi : 0;   // duplicate query -> identical bytes, benign
        const int p     = qlist[kq];
        const float ux = unknown[p * 3 + 0];
        const float uy = unknown[p * 3 + 1];
        const float uz = unknown[p * 3 + 2];

        float D0 = __builtin_inff(), D1 = __builtin_inff(), D2 = __builtin_inff();
        int   I0 = NM, I1 = NM, I2 = NM;

        // thread t handles point-pairs pr = i*16 + t  (points 2pr, 2pr+1), i = 0..63
#pragma unroll 8
        for (int i = 0; i < NM / (2 * TQ); ++i) {
            const int pr = (i << 4) | t;
            const float2 vx = kx2[pr];
            const float2 vy = ky2[pr];
            const float2 vz = kz2[pr];
            const int jLo = pr << 1;
            // strict rn, numpy association ((dx2+dy2)+dz2): selection bit-identical to ref
            const float dx0 = __fsub_rn(ux, vx.x);
            const float dy0 = __fsub_rn(uy, vy.x);
            const float dz0 = __fsub_rn(uz, vz.x);
            const float dx1 = __fsub_rn(ux, vx.y);
            const float dy1 = __fsub_rn(uy, vy.y);
            const float dz1 = __fsub_rn(uz, vz.y);
            const float dLo = __fadd_rn(__fadd_rn(__fmul_rn(dx0, dx0), __fmul_rn(dy0, dy0)),
                                        __fmul_rn(dz0, dz0));
            const float dHi = __fadd_rn(__fadd_rn(__fmul_rn(dx1, dx1), __fmul_rn(dy1, dy1)),
                                        __fmul_rn(dz1, dz1));
            MERGE3(dLo, jLo);
            MERGE3(dHi, jLo + 1);
        }

        // merge 16 partial top-3 lists (shfl_down tree; valid at group lane 0), broadcast
#pragma unroll
        for (int off = 8; off >= 1; off >>= 1) {
            const float e0d = __shfl_down(D0, off);
            const float e1d = __shfl_down(D1, off);
            const float e2d = __shfl_down(D2, off);
            const int   e0i = __shfl_down(I0, off);
            const int   e1i = __shfl_down(I1, off);
            const int   e2i = __shfl_down(I2, off);
            MERGE_DI(e0d, e0i);
            MERGE_DI(e1d, e1i);
            MERGE_DI(e2d, e2i);
        }
        const int src = lane & ~15;
        D0 = __shfl(D0, src); D1 = __shfl(D1, src); D2 = __shfl(D2, src);
        I0 = __shfl(I0, src); I1 = __shfl(I1, src); I2 = __shfl(I2, src);

        const float t0 = 1.0f / (sqrtf(D0) + EPSF);
        const float t1 = 1.0f / (sqrtf(D1) + EPSF);
        const float t2 = 1.0f / (sqrtf(D2) + EPSF);
        const float s  = t0 + t1 + t2;
        const float w0w = t0 / s, w1w = t1 / s, w2w = t2 / s;

        // gather from raw (B,C,m): column reads, L2/L3-resident (feats = 8 MB)
        const float* fb = feats + (size_t)b * NC * NM;
#pragma unroll
        for (int k = 0; k < 8; ++k) {
            const int c = t + (k << 4);            // 16 lanes -> 64B-coalesced out rows
            const float* fc = fb + (size_t)c * NM;
            const float f0 = fc[I0];
            const float f1 = fc[I1];
            const float f2 = fc[I2];
            out[(size_t)p * NC + c] = w0w * f0 + w1w * f1 + w2w * f2;
        }
    }
}

extern "C" void kernel_launch(void* const* d_in, const int* in_sizes, int n_in,
                              void* d_out, int out_size, void* d_ws, size_t ws_size,
                              hipStream_t stream) {
    const float* unknown = (const float*)d_in[0];   // (n, 3)
    const float* known   = (const float*)d_in[1];   // (B, m, 3)
    const int*   binds   = (const int*)d_in[2];     // (n,)
    const float* feats   = (const float*)d_in[3];   // (B, C, m)
    float*       out     = (float*)d_out;           // (n, C, 1)

    fused<<<dim3(GX, NB), 256, 0, stream>>>(unknown, known, binds, feats, out);
}